// Round 14
// baseline (276.383 us; speedup 1.0000x reference)
//
#include <hip/hip_runtime.h>

// GCN 2-layer: atomic-free binning build + LDS-accumulated gathers.
// R4: float far-atomics wall (2634us). R11: CSR build atomics (~470us).
// R13: 272us; gather1 occupancy 19% (500 blocks), 3 random loads/edge.
// Now: NB=1000 bins (4 blocks/CU), 1-line-per-edge gathers (xpad row with
// embedded dinv; dz float2), decoupled per-tile cursors (0 far atomics).
constexpr int N_NODES = 100000;
constexpr int N_EDGES = 3200000;
constexpr int F1  = 16;    // hidden dim
constexpr int FIN = 5;     // input dim
constexpr int NPB = 100;   // nodes per bin
constexpr int NB  = N_NODES / NPB;           // 1000 bins (exact)
constexpr int TILE = 16384;                  // edges per tile
constexpr int NT  = (N_EDGES + TILE - 1) / TILE;  // 196 tiles
constexpr int TB  = 256;

// ---- 1: per-tile LDS histogram -> tile_cnt[tile*NB + b] (no atomics, no memset) ----
__global__ __launch_bounds__(256) void binhist_kernel(const int* __restrict__ dst,
                                                      int* __restrict__ tile_cnt) {
    __shared__ int lh[NB];
    int t = threadIdx.x;
    for (int b = t; b < NB; b += TB) lh[b] = 0;
    __syncthreads();
    int base = blockIdx.x * TILE;
#pragma unroll
    for (int k = 0; k < TILE / TB; ++k) {
        int e = base + k * TB + t;
        if (e < N_EDGES) atomicAdd(&lh[dst[e] / NPB], 1);
    }
    __syncthreads();
    int* row = tile_cnt + blockIdx.x * NB;
    for (int b = t; b < NB; b += TB) row[b] = lh[b];
}

// ---- 2: bin_cnt[b] = sum over tiles (coalesced column sum) ----
__global__ __launch_bounds__(256) void colsum_kernel(const int* __restrict__ tile_cnt,
                                                     int* __restrict__ bin_cnt) {
    int b = blockIdx.x * TB + threadIdx.x;
    if (b >= NB) return;
    int s = 0;
    for (int i = 0; i < NT; ++i) s += tile_cnt[i * NB + b];
    bin_cnt[b] = s;
}

// ---- 3: single-block exclusive scan of 1000 bin counts ----
__global__ __launch_bounds__(1024) void binscan_kernel(const int* __restrict__ bin_cnt,
                                                       int* __restrict__ bin_base) {
    __shared__ int buf[2][1024];
    int t = threadIdx.x;
    int v = (t < NB) ? bin_cnt[t] : 0;
    buf[0][t] = v;
    __syncthreads();
    int cur = 0;
    for (int off = 1; off < 1024; off <<= 1) {
        int nv = buf[cur][t];
        if (t >= off) nv += buf[cur][t - off];
        buf[cur ^ 1][t] = nv;
        cur ^= 1;
        __syncthreads();
    }
    if (t < NB) bin_base[t] = buf[cur][t] - v;
    if (t == 0) bin_base[NB] = N_EDGES;
}

// ---- 4: in-place per-bin tile-prefix: tile_cnt[i][b] <- write cursor ----
__global__ __launch_bounds__(256) void tilebase_kernel(int* __restrict__ tile_cnt,
                                                       const int* __restrict__ bin_base) {
    int b = blockIdx.x * TB + threadIdx.x;
    if (b >= NB) return;
    int run = bin_base[b];
    for (int i = 0; i < NT; ++i) {
        int c = tile_cnt[i * NB + b];
        tile_cnt[i * NB + b] = run;
        run += c;
    }
}

// ---- 5: repack x -> xpad[N][8] (slots 0..4 = x; 5 = dinv, written later) ----
__global__ __launch_bounds__(256) void repack_kernel(const float* __restrict__ x,
                                                     float* __restrict__ xpad) {
    int i = blockIdx.x * TB + threadIdx.x;
    if (i >= N_NODES) return;
#pragma unroll
    for (int k = 0; k < FIN; ++k) xpad[i * 8 + k] = x[i * FIN + k];
}

// ---- 6: reorder edges into bins (zero global atomics; LDS rank only) ----
__global__ __launch_bounds__(256) void reorder_kernel(const int* __restrict__ src,
                                                      const int* __restrict__ dst,
                                                      const int* __restrict__ tile_base,
                                                      int* __restrict__ binned) {
    __shared__ int lh[NB];
    __shared__ int lbase[NB];
    int t = threadIdx.x;
    const int* row = tile_base + blockIdx.x * NB;
    for (int b = t; b < NB; b += TB) { lh[b] = 0; lbase[b] = row[b]; }
    __syncthreads();
    int base = blockIdx.x * TILE;
#pragma unroll
    for (int k = 0; k < TILE / TB; ++k) {
        int e = base + k * TB + t;
        if (e < N_EDGES) {
            int d = dst[e];
            int b = d / NPB;
            int r = atomicAdd(&lh[b], 1);
            binned[lbase[b] + r] = src[e] | ((d - b * NPB) << 24);
        }
    }
}

// ---- 7: per-bin degree -> dinv into xpad[.,5] and dz.x ----
__global__ __launch_bounds__(256) void degbin_kernel(const int* __restrict__ binned,
                                                     const int* __restrict__ bin_base,
                                                     float* __restrict__ xpad,
                                                     float2* __restrict__ dz) {
    __shared__ int cnt[NPB];
    int t = threadIdx.x, b = blockIdx.x;
    if (t < NPB) cnt[t] = 0;
    __syncthreads();
    int s0 = bin_base[b], s1 = bin_base[b + 1];
    for (int e = s0 + t; e < s1; e += TB)
        atomicAdd(&cnt[((unsigned)binned[e]) >> 24], 1);
    __syncthreads();
    if (t < NPB) {
        int g = b * NPB + t;
        float dv = rsqrtf((float)cnt[t] + 1.0f);  // +1 self-loop
        xpad[g * 8 + 5] = dv;
        dz[g].x = dv;
    }
}

// ---- 8: layer-1 gather: one 64B line per edge; LDS float atomics;
//         z = relu(agg@W1 + b1)@W2 (aggregation commutes with W1) ----
__global__ __launch_bounds__(256) void gather1_kernel(const int* __restrict__ binned,
                                                      const int* __restrict__ bin_base,
                                                      const float* __restrict__ xpad,
                                                      const float* __restrict__ W1,
                                                      const float* __restrict__ b1,
                                                      const float* __restrict__ W2,
                                                      float2* __restrict__ dz) {
    __shared__ float agg[NPB * FIN];
    __shared__ float dinvL[NPB];
    int t = threadIdx.x, b = blockIdx.x;
    int g = b * NPB + t;
    if (t < NPB) {
        float dd = xpad[g * 8 + 5];
        dinvL[t] = dd;
        float di2 = dd * dd;
#pragma unroll
        for (int k = 0; k < FIN; ++k) agg[t * FIN + k] = di2 * xpad[g * 8 + k];
    }
    __syncthreads();
    int s0 = bin_base[b], s1 = bin_base[b + 1];
    for (int e = s0 + t; e < s1; e += TB) {
        int v = binned[e];
        int s = v & 0x00FFFFFF;
        int dl = ((unsigned)v) >> 24;
        const float* xr = xpad + s * 8;
        float4 x03 = *(const float4*)xr;   // 32B-aligned row: 1 cache line
        float x4 = xr[4];
        float w  = xr[5] * dinvL[dl];      // dinv[s] rides the same line
        atomicAdd(&agg[dl * FIN + 0], w * x03.x);
        atomicAdd(&agg[dl * FIN + 1], w * x03.y);
        atomicAdd(&agg[dl * FIN + 2], w * x03.z);
        atomicAdd(&agg[dl * FIN + 3], w * x03.w);
        atomicAdd(&agg[dl * FIN + 4], w * x4);
    }
    __syncthreads();
    if (t < NPB) {
        float a[FIN];
#pragma unroll
        for (int k = 0; k < FIN; ++k) a[k] = agg[t * FIN + k];
        float p = 0.f;
#pragma unroll
        for (int f = 0; f < F1; ++f) {
            float h = b1[f];
#pragma unroll
            for (int k = 0; k < FIN; ++k) h += a[k] * W1[k * F1 + f];
            p += fmaxf(h, 0.f) * W2[f];
        }
        dz[g].y = p;
    }
}

// ---- 9: layer-2 gather: one 8B load per edge ----
__global__ __launch_bounds__(256) void gather2_kernel(const int* __restrict__ binned,
                                                      const int* __restrict__ bin_base,
                                                      const float2* __restrict__ dz,
                                                      const float* __restrict__ b2,
                                                      float* __restrict__ out) {
    __shared__ float acc[NPB];
    __shared__ float dinvL[NPB];
    int t = threadIdx.x, b = blockIdx.x;
    int g = b * NPB + t;
    if (t < NPB) {
        float2 v = dz[g];
        dinvL[t] = v.x;
        acc[t] = v.x * v.y;   // self-loop seed (dd * z, final *dd below)
    }
    __syncthreads();
    int s0 = bin_base[b], s1 = bin_base[b + 1];
    for (int e = s0 + t; e < s1; e += TB) {
        int v = binned[e];
        float2 sv = dz[v & 0x00FFFFFF];
        atomicAdd(&acc[((unsigned)v) >> 24], sv.x * sv.y);
    }
    __syncthreads();
    if (t < NPB) out[g] = dinvL[t] * acc[t] + b2[0];
}

extern "C" void kernel_launch(void* const* d_in, const int* in_sizes, int n_in,
                              void* d_out, int out_size, void* d_ws, size_t ws_size,
                              hipStream_t stream) {
    const float* x  = (const float*)d_in[0];
    const int*   ei = (const int*)d_in[1];   // int32 per harness contract
    const float* W1 = (const float*)d_in[2];
    const float* b1 = (const float*)d_in[3];
    const float* W2 = (const float*)d_in[4];
    const float* b2 = (const float*)d_in[5];
    float* out = (float*)d_out;

    // ws: dz[N] float2 | xpad[N*8] f32 | binned[E] int | tile_cnt[NT*NB] | bin_cnt[NB] | bin_base[NB+1]
    // = 0.8 + 3.2 + 12.8 + 0.78 + ~0.01 MB  (~17.6 MB). Everything fully written per call.
    float2* dz       = (float2*)d_ws;
    float*  xpad     = (float*)(dz + N_NODES);
    int*    binned   = (int*)(xpad + N_NODES * 8);
    int*    tile_cnt = binned + N_EDGES;
    int*    bin_cnt  = tile_cnt + NT * NB;
    int*    bin_base = bin_cnt + NB;

    const int* src = ei;            // edge_index[0]
    const int* dst = ei + N_EDGES;  // edge_index[1]

    int gB = (NB + TB - 1) / TB;          // 4
    int gN = (N_NODES + TB - 1) / TB;     // 391

    binhist_kernel<<<NT, TB, 0, stream>>>(dst, tile_cnt);
    colsum_kernel<<<gB, TB, 0, stream>>>(tile_cnt, bin_cnt);
    binscan_kernel<<<1, 1024, 0, stream>>>(bin_cnt, bin_base);
    tilebase_kernel<<<gB, TB, 0, stream>>>(tile_cnt, bin_base);
    repack_kernel<<<gN, TB, 0, stream>>>(x, xpad);
    reorder_kernel<<<NT, TB, 0, stream>>>(src, dst, tile_cnt, binned);
    degbin_kernel<<<NB, TB, 0, stream>>>(binned, bin_base, xpad, dz);
    gather1_kernel<<<NB, TB, 0, stream>>>(binned, bin_base, xpad, W1, b1, W2, dz);
    gather2_kernel<<<NB, TB, 0, stream>>>(binned, bin_base, dz, b2, out);
}

// Round 15
// 253.400 us; speedup vs baseline: 1.0907x; 1.0907x over previous
//
#include <hip/hip_runtime.h>

// GCN 2-layer: atomic-free binning + LDS gathers, ILP-batched edge loops.
// R13->R14 lesson: gather1 is LATENCY-bound (dep chain binned->xpad->LDS),
// not occupancy/BW-bound. Fix: 4-edge batching (4x MLP), NB=2000 blocks,
// 512-thread binning kernels.
constexpr int N_NODES = 100000;
constexpr int N_EDGES = 3200000;
constexpr int F1  = 16;    // hidden dim
constexpr int FIN = 5;     // input dim
constexpr int NPB = 50;    // nodes per bin
constexpr int NB  = N_NODES / NPB;           // 2000 bins (exact)
constexpr int TILE = 16384;                  // edges per tile
constexpr int NT  = (N_EDGES + TILE - 1) / TILE;  // 196 tiles
constexpr int TB  = 256;
constexpr int BTB = 512;   // threads for binhist/reorder

// ---- 1: per-tile LDS histogram -> tile_cnt row (no global atomics) ----
__global__ __launch_bounds__(512) void binhist_kernel(const int4* __restrict__ dst4,
                                                      int* __restrict__ tile_cnt) {
    __shared__ int lh[NB];
    int t = threadIdx.x;
    for (int b = t; b < NB; b += BTB) lh[b] = 0;
    __syncthreads();
    int base4 = blockIdx.x * (TILE / 4);
#pragma unroll
    for (int k = 0; k < TILE / (4 * BTB); ++k) {   // 8
        int i4 = base4 + k * BTB + t;
        if (i4 * 4 < N_EDGES) {
            int4 d = dst4[i4];
            atomicAdd(&lh[d.x / NPB], 1);
            atomicAdd(&lh[d.y / NPB], 1);
            atomicAdd(&lh[d.z / NPB], 1);
            atomicAdd(&lh[d.w / NPB], 1);
        }
    }
    __syncthreads();
    int* row = tile_cnt + blockIdx.x * NB;
    for (int b = t; b < NB; b += BTB) row[b] = lh[b];
}

// ---- 2: bin_cnt[b] = column sum over tiles ----
__global__ __launch_bounds__(256) void colsum_kernel(const int* __restrict__ tile_cnt,
                                                     int* __restrict__ bin_cnt) {
    int b = blockIdx.x * TB + threadIdx.x;
    if (b >= NB) return;
    int s = 0;
    for (int i = 0; i < NT; ++i) s += tile_cnt[i * NB + b];
    bin_cnt[b] = s;
}

// ---- 3: single-block exclusive scan of 2000 counts (2/thread) ----
__global__ __launch_bounds__(1024) void binscan_kernel(const int* __restrict__ bin_cnt,
                                                       int* __restrict__ bin_base) {
    __shared__ int buf[2][1024];
    int t = threadIdx.x;
    int a0 = (2 * t     < NB) ? bin_cnt[2 * t]     : 0;
    int a1 = (2 * t + 1 < NB) ? bin_cnt[2 * t + 1] : 0;
    int p = a0 + a1;
    buf[0][t] = p;
    __syncthreads();
    int cur = 0;
    for (int off = 1; off < 1024; off <<= 1) {
        int nv = buf[cur][t];
        if (t >= off) nv += buf[cur][t - off];
        buf[cur ^ 1][t] = nv;
        cur ^= 1;
        __syncthreads();
    }
    int excl = buf[cur][t] - p;
    if (2 * t     < NB) bin_base[2 * t]     = excl;
    if (2 * t + 1 < NB) bin_base[2 * t + 1] = excl + a0;
    if (t == 0) bin_base[NB] = N_EDGES;
}

// ---- 4: per-bin tile-prefix: tile_cnt[i][b] <- write cursor ----
__global__ __launch_bounds__(256) void tilebase_kernel(int* __restrict__ tile_cnt,
                                                       const int* __restrict__ bin_base) {
    int b = blockIdx.x * TB + threadIdx.x;
    if (b >= NB) return;
    int run = bin_base[b];
    for (int i = 0; i < NT; ++i) {
        int c = tile_cnt[i * NB + b];
        tile_cnt[i * NB + b] = run;
        run += c;
    }
}

// ---- 5: repack x -> xpad[N][8] (slot 5 = dinv, written by degbin) ----
__global__ __launch_bounds__(256) void repack_kernel(const float* __restrict__ x,
                                                     float* __restrict__ xpad) {
    int i = blockIdx.x * TB + threadIdx.x;
    if (i >= N_NODES) return;
#pragma unroll
    for (int k = 0; k < FIN; ++k) xpad[i * 8 + k] = x[i * FIN + k];
}

// ---- 6: reorder edges into bins (LDS rank; no global atomics) ----
__global__ __launch_bounds__(512) void reorder_kernel(const int4* __restrict__ src4,
                                                      const int4* __restrict__ dst4,
                                                      const int* __restrict__ tile_base,
                                                      int* __restrict__ binned) {
    __shared__ int lh[NB];
    __shared__ int lbase[NB];
    int t = threadIdx.x;
    const int* row = tile_base + blockIdx.x * NB;
    for (int b = t; b < NB; b += BTB) { lh[b] = 0; lbase[b] = row[b]; }
    __syncthreads();
    int base4 = blockIdx.x * (TILE / 4);
#pragma unroll
    for (int k = 0; k < TILE / (4 * BTB); ++k) {   // 8
        int i4 = base4 + k * BTB + t;
        if (i4 * 4 < N_EDGES) {
            int4 d = dst4[i4];
            int4 s = src4[i4];
            int b0 = d.x / NPB, b1 = d.y / NPB, b2 = d.z / NPB, b3 = d.w / NPB;
            int r0 = atomicAdd(&lh[b0], 1);
            int r1 = atomicAdd(&lh[b1], 1);
            int r2 = atomicAdd(&lh[b2], 1);
            int r3 = atomicAdd(&lh[b3], 1);
            binned[lbase[b0] + r0] = s.x | ((d.x - b0 * NPB) << 24);
            binned[lbase[b1] + r1] = s.y | ((d.y - b1 * NPB) << 24);
            binned[lbase[b2] + r2] = s.z | ((d.z - b2 * NPB) << 24);
            binned[lbase[b3] + r3] = s.w | ((d.w - b3 * NPB) << 24);
        }
    }
}

// ---- 7: per-bin degree -> dinv (xpad slot 5 + dz.x), 4-batched ----
__global__ __launch_bounds__(256) void degbin_kernel(const int* __restrict__ binned,
                                                     const int* __restrict__ bin_base,
                                                     float* __restrict__ xpad,
                                                     float2* __restrict__ dz) {
    __shared__ int cnt[NPB];
    int t = threadIdx.x, b = blockIdx.x;
    if (t < NPB) cnt[t] = 0;
    __syncthreads();
    int s0 = bin_base[b], s1 = bin_base[b + 1];
    int e = s0 + t;
    for (; e + 3 * TB < s1; e += 4 * TB) {
        int v0 = binned[e], v1 = binned[e + TB], v2 = binned[e + 2 * TB], v3 = binned[e + 3 * TB];
        atomicAdd(&cnt[((unsigned)v0) >> 24], 1);
        atomicAdd(&cnt[((unsigned)v1) >> 24], 1);
        atomicAdd(&cnt[((unsigned)v2) >> 24], 1);
        atomicAdd(&cnt[((unsigned)v3) >> 24], 1);
    }
    for (; e < s1; e += TB)
        atomicAdd(&cnt[((unsigned)binned[e]) >> 24], 1);
    __syncthreads();
    if (t < NPB) {
        int g = b * NPB + t;
        float dv = rsqrtf((float)cnt[t] + 1.0f);  // +1 self-loop
        xpad[g * 8 + 5] = dv;
        dz[g].x = dv;
    }
}

// ---- 8: layer-1 gather, 4-batched; z = relu(agg@W1+b1)@W2 ----
__global__ __launch_bounds__(256) void gather1_kernel(const int* __restrict__ binned,
                                                      const int* __restrict__ bin_base,
                                                      const float* __restrict__ xpad,
                                                      const float* __restrict__ W1,
                                                      const float* __restrict__ b1,
                                                      const float* __restrict__ W2,
                                                      float2* __restrict__ dz) {
    __shared__ float agg[NPB * FIN];
    __shared__ float dinvL[NPB];
    int t = threadIdx.x, b = blockIdx.x;
    int g = b * NPB + t;
    if (t < NPB) {
        float dd = xpad[g * 8 + 5];
        dinvL[t] = dd;
        float di2 = dd * dd;
#pragma unroll
        for (int k = 0; k < FIN; ++k) agg[t * FIN + k] = di2 * xpad[g * 8 + k];
    }
    __syncthreads();
    int s0 = bin_base[b], s1 = bin_base[b + 1];
    int e = s0 + t;
    for (; e + 3 * TB < s1; e += 4 * TB) {
        int v0 = binned[e], v1 = binned[e + TB], v2 = binned[e + 2 * TB], v3 = binned[e + 3 * TB];
        const float* r0 = xpad + (v0 & 0xFFFFFF) * 8;
        const float* r1 = xpad + (v1 & 0xFFFFFF) * 8;
        const float* r2 = xpad + (v2 & 0xFFFFFF) * 8;
        const float* r3 = xpad + (v3 & 0xFFFFFF) * 8;
        float4 q0 = *(const float4*)r0; float c0 = r0[4], u0 = r0[5];
        float4 q1 = *(const float4*)r1; float c1 = r1[4], u1 = r1[5];
        float4 q2 = *(const float4*)r2; float c2 = r2[4], u2 = r2[5];
        float4 q3 = *(const float4*)r3; float c3 = r3[4], u3 = r3[5];
        int d0 = ((unsigned)v0) >> 24; float w0 = u0 * dinvL[d0];
        int d1 = ((unsigned)v1) >> 24; float w1 = u1 * dinvL[d1];
        int d2 = ((unsigned)v2) >> 24; float w2 = u2 * dinvL[d2];
        int d3 = ((unsigned)v3) >> 24; float w3 = u3 * dinvL[d3];
        atomicAdd(&agg[d0 * FIN + 0], w0 * q0.x); atomicAdd(&agg[d0 * FIN + 1], w0 * q0.y);
        atomicAdd(&agg[d0 * FIN + 2], w0 * q0.z); atomicAdd(&agg[d0 * FIN + 3], w0 * q0.w);
        atomicAdd(&agg[d0 * FIN + 4], w0 * c0);
        atomicAdd(&agg[d1 * FIN + 0], w1 * q1.x); atomicAdd(&agg[d1 * FIN + 1], w1 * q1.y);
        atomicAdd(&agg[d1 * FIN + 2], w1 * q1.z); atomicAdd(&agg[d1 * FIN + 3], w1 * q1.w);
        atomicAdd(&agg[d1 * FIN + 4], w1 * c1);
        atomicAdd(&agg[d2 * FIN + 0], w2 * q2.x); atomicAdd(&agg[d2 * FIN + 1], w2 * q2.y);
        atomicAdd(&agg[d2 * FIN + 2], w2 * q2.z); atomicAdd(&agg[d2 * FIN + 3], w2 * q2.w);
        atomicAdd(&agg[d2 * FIN + 4], w2 * c2);
        atomicAdd(&agg[d3 * FIN + 0], w3 * q3.x); atomicAdd(&agg[d3 * FIN + 1], w3 * q3.y);
        atomicAdd(&agg[d3 * FIN + 2], w3 * q3.z); atomicAdd(&agg[d3 * FIN + 3], w3 * q3.w);
        atomicAdd(&agg[d3 * FIN + 4], w3 * c3);
    }
    for (; e < s1; e += TB) {
        int v = binned[e];
        const float* r = xpad + (v & 0xFFFFFF) * 8;
        float4 q = *(const float4*)r; float c = r[4];
        int dl = ((unsigned)v) >> 24;
        float w = r[5] * dinvL[dl];
        atomicAdd(&agg[dl * FIN + 0], w * q.x); atomicAdd(&agg[dl * FIN + 1], w * q.y);
        atomicAdd(&agg[dl * FIN + 2], w * q.z); atomicAdd(&agg[dl * FIN + 3], w * q.w);
        atomicAdd(&agg[dl * FIN + 4], w * c);
    }
    __syncthreads();
    if (t < NPB) {
        float a[FIN];
#pragma unroll
        for (int k = 0; k < FIN; ++k) a[k] = agg[t * FIN + k];
        float p = 0.f;
#pragma unroll
        for (int f = 0; f < F1; ++f) {
            float h = b1[f];
#pragma unroll
            for (int k = 0; k < FIN; ++k) h += a[k] * W1[k * F1 + f];
            p += fmaxf(h, 0.f) * W2[f];
        }
        dz[g].y = p;
    }
}

// ---- 9: layer-2 gather, 4-batched; one 8B load per edge ----
__global__ __launch_bounds__(256) void gather2_kernel(const int* __restrict__ binned,
                                                      const int* __restrict__ bin_base,
                                                      const float2* __restrict__ dz,
                                                      const float* __restrict__ b2,
                                                      float* __restrict__ out) {
    __shared__ float acc[NPB];
    __shared__ float dinvL[NPB];
    int t = threadIdx.x, b = blockIdx.x;
    int g = b * NPB + t;
    if (t < NPB) {
        float2 v = dz[g];
        dinvL[t] = v.x;
        acc[t] = v.x * v.y;   // self-loop seed
    }
    __syncthreads();
    int s0 = bin_base[b], s1 = bin_base[b + 1];
    int e = s0 + t;
    for (; e + 3 * TB < s1; e += 4 * TB) {
        int v0 = binned[e], v1 = binned[e + TB], v2 = binned[e + 2 * TB], v3 = binned[e + 3 * TB];
        float2 a0 = dz[v0 & 0xFFFFFF];
        float2 a1 = dz[v1 & 0xFFFFFF];
        float2 a2 = dz[v2 & 0xFFFFFF];
        float2 a3 = dz[v3 & 0xFFFFFF];
        atomicAdd(&acc[((unsigned)v0) >> 24], a0.x * a0.y);
        atomicAdd(&acc[((unsigned)v1) >> 24], a1.x * a1.y);
        atomicAdd(&acc[((unsigned)v2) >> 24], a2.x * a2.y);
        atomicAdd(&acc[((unsigned)v3) >> 24], a3.x * a3.y);
    }
    for (; e < s1; e += TB) {
        int v = binned[e];
        float2 a = dz[v & 0xFFFFFF];
        atomicAdd(&acc[((unsigned)v) >> 24], a.x * a.y);
    }
    __syncthreads();
    if (t < NPB) out[g] = dinvL[t] * acc[t] + b2[0];
}

extern "C" void kernel_launch(void* const* d_in, const int* in_sizes, int n_in,
                              void* d_out, int out_size, void* d_ws, size_t ws_size,
                              hipStream_t stream) {
    const float* x  = (const float*)d_in[0];
    const int*   ei = (const int*)d_in[1];   // int32 per harness contract
    const float* W1 = (const float*)d_in[2];
    const float* b1 = (const float*)d_in[3];
    const float* W2 = (const float*)d_in[4];
    const float* b2 = (const float*)d_in[5];
    float* out = (float*)d_out;

    // ws: dz[N] float2 | xpad[N*8] | binned[E] | tile_cnt[NT*NB] | bin_cnt[NB] | bin_base[NB+1]
    // = 0.8 + 3.2 + 12.8 + 1.57 + 0.016 MB  (~18.4 MB). All fully rewritten per call.
    float2* dz       = (float2*)d_ws;
    float*  xpad     = (float*)(dz + N_NODES);
    int*    binned   = (int*)(xpad + N_NODES * 8);
    int*    tile_cnt = binned + N_EDGES;
    int*    bin_cnt  = tile_cnt + NT * NB;
    int*    bin_base = bin_cnt + NB;

    const int4* src4 = (const int4*)ei;                 // edge_index[0]
    const int4* dst4 = (const int4*)(ei + N_EDGES);     // edge_index[1]

    int gB = (NB + TB - 1) / TB;          // 8
    int gN = (N_NODES + TB - 1) / TB;     // 391

    binhist_kernel<<<NT, BTB, 0, stream>>>(dst4, tile_cnt);
    colsum_kernel<<<gB, TB, 0, stream>>>(tile_cnt, bin_cnt);
    binscan_kernel<<<1, 1024, 0, stream>>>(bin_cnt, bin_base);
    tilebase_kernel<<<gB, TB, 0, stream>>>(tile_cnt, bin_base);
    repack_kernel<<<gN, TB, 0, stream>>>(x, xpad);
    reorder_kernel<<<NT, BTB, 0, stream>>>(src4, dst4, tile_cnt, binned);
    degbin_kernel<<<NB, TB, 0, stream>>>(binned, bin_base, xpad, dz);
    gather1_kernel<<<NB, TB, 0, stream>>>(binned, bin_base, xpad, W1, b1, W2, dz);
    gather2_kernel<<<NB, TB, 0, stream>>>(binned, bin_base, dz, b2, out);
}

// Round 18
// 199.737 us; speedup vs baseline: 1.3837x; 1.2687x over previous
//
#include <hip/hip_runtime.h>

// GCN 2-layer: full two-level counting sort -> per-node CSR -> atomic-free
// register-accumulated gathers.
// Evidence trail: R4 float far-atomics (2634us) -> R11 CSR-build far-atomics
// (652us) -> R13/14/15 gather1 INVARIANT at ~90us across occupancy x2.5 and
// ILP x4 => shared-resource cap = 5 LDS atomics/edge through the per-CU DS
// pipe. This version: gathers have ZERO atomics (thread-per-node run scan).
constexpr int N_NODES = 100000;
constexpr int N_EDGES = 3200000;
constexpr int F1  = 16;    // hidden dim
constexpr int FIN = 5;     // input dim
constexpr int NPB = 256;   // nodes per bin -> bin = d>>8, dl = d&255
constexpr int NB  = (N_NODES + NPB - 1) / NPB;      // 391
constexpr int TILE = 16384;
constexpr int NT  = (N_EDGES + TILE - 1) / TILE;    // 196
constexpr int TB  = 256;
constexpr int BTB = 512;

// ---- 1: per-tile LDS histogram -> tile_cnt row (no global atomics) ----
__global__ __launch_bounds__(512) void binhist_kernel(const int4* __restrict__ dst4,
                                                      int* __restrict__ tile_cnt) {
    __shared__ int lh[NB];
    int t = threadIdx.x;
    for (int b = t; b < NB; b += BTB) lh[b] = 0;
    __syncthreads();
    int base4 = blockIdx.x * (TILE / 4);
#pragma unroll
    for (int k = 0; k < TILE / (4 * BTB); ++k) {   // 8
        int i4 = base4 + k * BTB + t;
        if (i4 * 4 < N_EDGES) {
            int4 d = dst4[i4];
            atomicAdd(&lh[d.x >> 8], 1);
            atomicAdd(&lh[d.y >> 8], 1);
            atomicAdd(&lh[d.z >> 8], 1);
            atomicAdd(&lh[d.w >> 8], 1);
        }
    }
    __syncthreads();
    int* row = tile_cnt + blockIdx.x * NB;
    for (int b = t; b < NB; b += BTB) row[b] = lh[b];
}

// ---- 2: bin_cnt[b] = column sum over tiles ----
__global__ __launch_bounds__(256) void colsum_kernel(const int* __restrict__ tile_cnt,
                                                     int* __restrict__ bin_cnt) {
    int b = blockIdx.x * TB + threadIdx.x;
    if (b >= NB) return;
    int s = 0;
    for (int i = 0; i < NT; ++i) s += tile_cnt[i * NB + b];
    bin_cnt[b] = s;
}

// ---- 3: single-block exclusive scan of 391 bin counts ----
__global__ __launch_bounds__(512) void binscan_kernel(const int* __restrict__ bin_cnt,
                                                      int* __restrict__ bin_base) {
    __shared__ int buf[2][512];
    int t = threadIdx.x;
    int v = (t < NB) ? bin_cnt[t] : 0;
    buf[0][t] = v;
    __syncthreads();
    int cur = 0;
    for (int off = 1; off < 512; off <<= 1) {
        int nv = buf[cur][t];
        if (t >= off) nv += buf[cur][t - off];
        buf[cur ^ 1][t] = nv;
        cur ^= 1;
        __syncthreads();
    }
    if (t < NB) bin_base[t] = buf[cur][t] - v;
    if (t == 0) bin_base[NB] = N_EDGES;
}

// ---- 4: per-bin tile-prefix: tile_cnt[i][b] <- write cursor ----
__global__ __launch_bounds__(256) void tilebase_kernel(int* __restrict__ tile_cnt,
                                                       const int* __restrict__ bin_base) {
    int b = blockIdx.x * TB + threadIdx.x;
    if (b >= NB) return;
    int run = bin_base[b];
    for (int i = 0; i < NT; ++i) {
        int c = tile_cnt[i * NB + b];
        tile_cnt[i * NB + b] = run;
        run += c;
    }
}

// ---- 5: repack x -> xpad[N][8] (slots 0..4; scaled by dinv later) ----
__global__ __launch_bounds__(256) void repack_kernel(const float* __restrict__ x,
                                                     float* __restrict__ xpad) {
    int i = blockIdx.x * TB + threadIdx.x;
    if (i >= N_NODES) return;
#pragma unroll
    for (int k = 0; k < FIN; ++k) xpad[(size_t)i * 8 + k] = x[i * FIN + k];
}

// ---- 6: reorder edges into bins: binned = src | (dl<<24) ----
__global__ __launch_bounds__(512) void reorder_kernel(const int4* __restrict__ src4,
                                                      const int4* __restrict__ dst4,
                                                      const int* __restrict__ tile_base,
                                                      int* __restrict__ binned) {
    __shared__ int lh[NB];
    __shared__ int lbase[NB];
    int t = threadIdx.x;
    const int* row = tile_base + blockIdx.x * NB;
    for (int b = t; b < NB; b += BTB) { lh[b] = 0; lbase[b] = row[b]; }
    __syncthreads();
    int base4 = blockIdx.x * (TILE / 4);
#pragma unroll
    for (int k = 0; k < TILE / (4 * BTB); ++k) {   // 8
        int i4 = base4 + k * BTB + t;
        if (i4 * 4 < N_EDGES) {
            int4 d = dst4[i4];
            int4 s = src4[i4];
            int b0 = d.x >> 8, b1 = d.y >> 8, b2 = d.z >> 8, b3 = d.w >> 8;
            int r0 = atomicAdd(&lh[b0], 1);
            int r1 = atomicAdd(&lh[b1], 1);
            int r2 = atomicAdd(&lh[b2], 1);
            int r3 = atomicAdd(&lh[b3], 1);
            binned[lbase[b0] + r0] = s.x | ((d.x & 255) << 24);
            binned[lbase[b1] + r1] = s.y | ((d.y & 255) << 24);
            binned[lbase[b2] + r2] = s.z | ((d.z & 255) << 24);
            binned[lbase[b3] + r3] = s.w | ((d.w & 255) << 24);
        }
    }
}

// ---- 7: per-bin node CSR: count, dinv, scale xpad in place, scan,
//         node_base, dst-sorted re-place into binned2 ----
__global__ __launch_bounds__(256) void nodecsr_kernel(const int* __restrict__ binned,
                                                      const int* __restrict__ bin_base,
                                                      float* __restrict__ xpad,
                                                      int* __restrict__ node_base,
                                                      int* __restrict__ binned2) {
    __shared__ int cnt[NPB];
    __shared__ int sb[2][NPB];
    __shared__ int cur[NPB];
    int t = threadIdx.x, b = blockIdx.x;
    cnt[t] = 0;
    __syncthreads();
    int s0 = bin_base[b], s1 = bin_base[b + 1];
    int e = s0 + t;
    for (; e + 3 * TB < s1; e += 4 * TB) {
        int v0 = binned[e], v1 = binned[e + TB], v2 = binned[e + 2 * TB], v3 = binned[e + 3 * TB];
        atomicAdd(&cnt[((unsigned)v0) >> 24], 1);
        atomicAdd(&cnt[((unsigned)v1) >> 24], 1);
        atomicAdd(&cnt[((unsigned)v2) >> 24], 1);
        atomicAdd(&cnt[((unsigned)v3) >> 24], 1);
    }
    for (; e < s1; e += TB) atomicAdd(&cnt[((unsigned)binned[e]) >> 24], 1);
    __syncthreads();
    int myc = cnt[t];
    // exclusive scan of 256 counts
    sb[0][t] = myc;
    __syncthreads();
    int c = 0;
    for (int off = 1; off < NPB; off <<= 1) {
        int nv = sb[c][t];
        if (t >= off) nv += sb[c][t - off];
        sb[c ^ 1][t] = nv;
        c ^= 1;
        __syncthreads();
    }
    int excl = sb[c][t] - myc;
    cur[t] = excl;
    int g = b * NPB + t;
    if (g < N_NODES) {
        node_base[g] = s0 + excl;
        float dv = rsqrtf((float)myc + 1.0f);   // +1 self-loop
        float* row = xpad + (size_t)g * 8;
#pragma unroll
        for (int k = 0; k < FIN; ++k) row[k] *= dv;   // xs = dinv * x
        row[5] = dv;
    }
    if (b == NB - 1 && t == 0) node_base[N_NODES] = N_EDGES;
    __syncthreads();
    // place dst-sorted (1 LDS int atomic per edge)
    e = s0 + t;
    for (; e < s1; e += TB) {
        int v = binned[e];
        int r = atomicAdd(&cur[((unsigned)v) >> 24], 1);
        binned2[s0 + r] = v & 0x00FFFFFF;
    }
}

// ---- 8: layer-1 gather: thread-per-node run scan, ZERO atomics ----
__global__ __launch_bounds__(256) void gather1_kernel(const int* __restrict__ binned2,
                                                      const int* __restrict__ node_base,
                                                      const float* __restrict__ xpad,
                                                      const float* __restrict__ W1,
                                                      const float* __restrict__ b1,
                                                      const float* __restrict__ W2,
                                                      float* __restrict__ zs) {
    int g = blockIdx.x * TB + threadIdx.x;
    if (g >= N_NODES) return;
    int s = node_base[g], e1 = node_base[g + 1];
    const float* own = xpad + (size_t)g * 8;
    float4 o4 = *(const float4*)own;
    float acc0 = o4.x, acc1 = o4.y, acc2 = o4.z, acc3 = o4.w, acc4 = own[4];  // self term xs[d]
    float dd = own[5];
    int e = s;
    for (; e + 3 < e1; e += 4) {
        int a = binned2[e], bq = binned2[e + 1], cq = binned2[e + 2], dq = binned2[e + 3];
        const float* r0 = xpad + (size_t)a * 8;
        const float* r1 = xpad + (size_t)bq * 8;
        const float* r2 = xpad + (size_t)cq * 8;
        const float* r3 = xpad + (size_t)dq * 8;
        float4 q0 = *(const float4*)r0, q1 = *(const float4*)r1;
        float4 q2 = *(const float4*)r2, q3 = *(const float4*)r3;
        float c0 = r0[4], c1 = r1[4], c2 = r2[4], c3 = r3[4];
        acc0 += (q0.x + q1.x) + (q2.x + q3.x);
        acc1 += (q0.y + q1.y) + (q2.y + q3.y);
        acc2 += (q0.z + q1.z) + (q2.z + q3.z);
        acc3 += (q0.w + q1.w) + (q2.w + q3.w);
        acc4 += (c0 + c1) + (c2 + c3);
    }
    for (; e < e1; ++e) {
        const float* r = xpad + (size_t)binned2[e] * 8;
        float4 q = *(const float4*)r;
        acc0 += q.x; acc1 += q.y; acc2 += q.z; acc3 += q.w; acc4 += r[4];
    }
    float a0 = dd * acc0, a1 = dd * acc1, a2 = dd * acc2, a3 = dd * acc3, a4 = dd * acc4;
    float p = 0.f;
#pragma unroll
    for (int f = 0; f < F1; ++f) {
        float h = b1[f] + a0 * W1[0 * F1 + f] + a1 * W1[1 * F1 + f] + a2 * W1[2 * F1 + f]
                        + a3 * W1[3 * F1 + f] + a4 * W1[4 * F1 + f];
        p += fmaxf(h, 0.f) * W2[f];
    }
    zs[g] = dd * p;   // zs = dinv * z
}

// ---- 9: layer-2 gather: thread-per-node, out = dd*(sum zs[s] + zs[d]) + b2 ----
__global__ __launch_bounds__(256) void gather2_kernel(const int* __restrict__ binned2,
                                                      const int* __restrict__ node_base,
                                                      const float* __restrict__ zs,
                                                      const float* __restrict__ xpad,
                                                      const float* __restrict__ b2,
                                                      float* __restrict__ out) {
    int g = blockIdx.x * TB + threadIdx.x;
    if (g >= N_NODES) return;
    int s = node_base[g], e1 = node_base[g + 1];
    float acc = zs[g];   // self term
    int e = s;
    for (; e + 3 < e1; e += 4) {
        float z0 = zs[binned2[e]], z1 = zs[binned2[e + 1]];
        float z2 = zs[binned2[e + 2]], z3 = zs[binned2[e + 3]];
        acc += (z0 + z1) + (z2 + z3);
    }
    for (; e < e1; ++e) acc += zs[binned2[e]];
    out[g] = xpad[(size_t)g * 8 + 5] * acc + b2[0];
}

extern "C" void kernel_launch(void* const* d_in, const int* in_sizes, int n_in,
                              void* d_out, int out_size, void* d_ws, size_t ws_size,
                              hipStream_t stream) {
    const float* x  = (const float*)d_in[0];
    const int*   ei = (const int*)d_in[1];   // int32 per harness contract
    const float* W1 = (const float*)d_in[2];
    const float* b1 = (const float*)d_in[3];
    const float* W2 = (const float*)d_in[4];
    const float* b2 = (const float*)d_in[5];
    float* out = (float*)d_out;

    // ws layout (~30 MB): xpad[N*8] | binned[E] | binned2[E] | zs[N] |
    //                     node_base[N+1] | tile_cnt[NT*NB] | bin_cnt[NB] | bin_base[NB+1]
    float* xpad      = (float*)d_ws;                  // 16B-aligned base
    int*   binned    = (int*)(xpad + (size_t)N_NODES * 8);
    int*   binned2   = binned + N_EDGES;
    float* zs        = (float*)(binned2 + N_EDGES);
    int*   node_base = (int*)(zs + N_NODES);
    int*   tile_cnt  = node_base + N_NODES + 1;
    int*   bin_cnt   = tile_cnt + NT * NB;
    int*   bin_base  = bin_cnt + NB;

    const int4* src4 = (const int4*)ei;               // edge_index[0]
    const int4* dst4 = (const int4*)(ei + N_EDGES);   // edge_index[1]

    int gB = (NB + TB - 1) / TB;          // 2
    int gN = (N_NODES + TB - 1) / TB;     // 391

    binhist_kernel<<<NT, BTB, 0, stream>>>(dst4, tile_cnt);
    colsum_kernel<<<gB, TB, 0, stream>>>(tile_cnt, bin_cnt);
    binscan_kernel<<<1, 512, 0, stream>>>(bin_cnt, bin_base);
    tilebase_kernel<<<gB, TB, 0, stream>>>(tile_cnt, bin_base);
    repack_kernel<<<gN, TB, 0, stream>>>(x, xpad);
    reorder_kernel<<<NT, BTB, 0, stream>>>(src4, dst4, tile_cnt, binned);
    nodecsr_kernel<<<NB, TB, 0, stream>>>(binned, bin_base, xpad, node_base, binned2);
    gather1_kernel<<<gN, TB, 0, stream>>>(binned2, node_base, xpad, W1, b1, W2, zs);
    gather2_kernel<<<gN, TB, 0, stream>>>(binned2, node_base, zs, xpad, b2, out);
}

// Round 19
// 178.548 us; speedup vs baseline: 1.5479x; 1.1187x over previous
//
#include <hip/hip_runtime.h>

// GCN 2-layer: two-level counting sort + atomic-free register gathers, v2.
// R18 confirmed DS-atomic theory (zero-atomic gathers: 253->200us, gather1
// off top-5). Remaining cost: 4 LDS atomics/edge in sort + 9 launches.
// v2: fused scan kernels, fused place+gather (LDS-staged, coalesced binned2
// write), 2-replica histograms to halve contention.
constexpr int N_NODES = 100000;
constexpr int N_EDGES = 3200000;
constexpr int F1  = 16;    // hidden dim
constexpr int FIN = 5;     // input dim
constexpr int NPB = 256;   // bin = d>>8, dl = d&255
constexpr int NB  = (N_NODES + NPB - 1) / NPB;      // 391
constexpr int TILE = 16384;
constexpr int NT  = (N_EDGES + TILE - 1) / TILE;    // 196
constexpr int TB  = 256;
constexpr int BTB = 512;
constexpr int SCAP = 16384;  // LDS edge-stage cap (bin avg 8184, +91 sigma)

// ---- 1: per-tile histogram, 2 LDS replicas (wave-indexed) ----
__global__ __launch_bounds__(512) void binhist_kernel(const int4* __restrict__ dst4,
                                                      int* __restrict__ tile_cnt) {
    __shared__ int lh[2 * NB];
    int t = threadIdx.x;
    for (int b = t; b < 2 * NB; b += BTB) lh[b] = 0;
    __syncthreads();
    int rep = ((t >> 6) & 1) * NB;
    int base4 = blockIdx.x * (TILE / 4);
#pragma unroll
    for (int k = 0; k < TILE / (4 * BTB); ++k) {   // 8
        int i4 = base4 + k * BTB + t;
        if (i4 * 4 < N_EDGES) {
            int4 d = dst4[i4];
            atomicAdd(&lh[rep + (d.x >> 8)], 1);
            atomicAdd(&lh[rep + (d.y >> 8)], 1);
            atomicAdd(&lh[rep + (d.z >> 8)], 1);
            atomicAdd(&lh[rep + (d.w >> 8)], 1);
        }
    }
    __syncthreads();
    int* row = tile_cnt + blockIdx.x * NB;
    for (int b = t; b < NB; b += BTB) row[b] = lh[b] + lh[NB + b];
}

// ---- 2: fused colsum + exclusive scan + per-bin tile cursors (1 block) ----
__global__ __launch_bounds__(512) void scanfuse_kernel(int* __restrict__ tile_cnt,
                                                       int* __restrict__ bin_base) {
    __shared__ int sb[2][512];
    int t = threadIdx.x;
    int v = 0;
    if (t < NB)
        for (int i = 0; i < NT; ++i) v += tile_cnt[i * NB + t];
    sb[0][t] = v;
    __syncthreads();
    int cur = 0;
    for (int off = 1; off < 512; off <<= 1) {
        int nv = sb[cur][t];
        if (t >= off) nv += sb[cur][t - off];
        sb[cur ^ 1][t] = nv;
        cur ^= 1;
        __syncthreads();
    }
    int excl = sb[cur][t] - v;
    if (t < NB) bin_base[t] = excl;
    if (t == 0) bin_base[NB] = N_EDGES;
    if (t < NB) {
        int run = excl;
        for (int i = 0; i < NT; ++i) {
            int c = tile_cnt[i * NB + t];
            tile_cnt[i * NB + t] = run;
            run += c;
        }
    }
}

// ---- 3: repack x -> xpad[N][8] (slots 0..4; scaled by degscale later) ----
__global__ __launch_bounds__(256) void repack_kernel(const float* __restrict__ x,
                                                     float* __restrict__ xpad) {
    int i = blockIdx.x * TB + threadIdx.x;
    if (i >= N_NODES) return;
#pragma unroll
    for (int k = 0; k < FIN; ++k) xpad[(size_t)i * 8 + k] = x[i * FIN + k];
}

// ---- 4: reorder edges into bins: binned = src | (dl<<24) ----
__global__ __launch_bounds__(512) void reorder_kernel(const int4* __restrict__ src4,
                                                      const int4* __restrict__ dst4,
                                                      const int* __restrict__ tile_base,
                                                      int* __restrict__ binned) {
    __shared__ int lh[NB];
    __shared__ int lbase[NB];
    int t = threadIdx.x;
    const int* row = tile_base + blockIdx.x * NB;
    for (int b = t; b < NB; b += BTB) { lh[b] = 0; lbase[b] = row[b]; }
    __syncthreads();
    int base4 = blockIdx.x * (TILE / 4);
#pragma unroll
    for (int k = 0; k < TILE / (4 * BTB); ++k) {   // 8
        int i4 = base4 + k * BTB + t;
        if (i4 * 4 < N_EDGES) {
            int4 d = dst4[i4];
            int4 s = src4[i4];
            int b0 = d.x >> 8, b1 = d.y >> 8, b2 = d.z >> 8, b3 = d.w >> 8;
            int r0 = atomicAdd(&lh[b0], 1);
            int r1 = atomicAdd(&lh[b1], 1);
            int r2 = atomicAdd(&lh[b2], 1);
            int r3 = atomicAdd(&lh[b3], 1);
            binned[lbase[b0] + r0] = s.x | ((d.x & 255) << 24);
            binned[lbase[b1] + r1] = s.y | ((d.y & 255) << 24);
            binned[lbase[b2] + r2] = s.z | ((d.z & 255) << 24);
            binned[lbase[b3] + r3] = s.w | ((d.w & 255) << 24);
        }
    }
}

// ---- 5: per-bin degree (2-replica count) -> node_base, dinv, xpad scale ----
__global__ __launch_bounds__(256) void degscale_kernel(const int* __restrict__ binned,
                                                       const int* __restrict__ bin_base,
                                                       float* __restrict__ xpad,
                                                       int* __restrict__ node_base) {
    __shared__ int cnt[2 * NPB];
    __shared__ int sb[2][NPB];
    int t = threadIdx.x, b = blockIdx.x;
    cnt[t] = 0; cnt[NPB + t] = 0;
    __syncthreads();
    int s0 = bin_base[b], s1 = bin_base[b + 1];
    int rep = ((t >> 6) & 1) * NPB;
    int e = s0 + t;
    for (; e + 3 * TB < s1; e += 4 * TB) {
        int v0 = binned[e], v1 = binned[e + TB], v2 = binned[e + 2 * TB], v3 = binned[e + 3 * TB];
        atomicAdd(&cnt[rep + (((unsigned)v0) >> 24)], 1);
        atomicAdd(&cnt[rep + (((unsigned)v1) >> 24)], 1);
        atomicAdd(&cnt[rep + (((unsigned)v2) >> 24)], 1);
        atomicAdd(&cnt[rep + (((unsigned)v3) >> 24)], 1);
    }
    for (; e < s1; e += TB) atomicAdd(&cnt[rep + (((unsigned)binned[e]) >> 24)], 1);
    __syncthreads();
    int myc = cnt[t] + cnt[NPB + t];
    sb[0][t] = myc;
    __syncthreads();
    int c = 0;
    for (int off = 1; off < NPB; off <<= 1) {
        int nv = sb[c][t];
        if (t >= off) nv += sb[c][t - off];
        sb[c ^ 1][t] = nv;
        c ^= 1;
        __syncthreads();
    }
    int excl = sb[c][t] - myc;
    int g = b * NPB + t;
    if (g < N_NODES) {
        node_base[g] = s0 + excl;
        float dv = rsqrtf((float)myc + 1.0f);   // +1 self-loop
        float* row = xpad + (size_t)g * 8;
#pragma unroll
        for (int k = 0; k < FIN; ++k) row[k] *= dv;   // xs = dinv * x
        row[5] = dv;
    }
    if (b == NB - 1 && t == 0) node_base[N_NODES] = N_EDGES;
}

// ---- 6: fused place (LDS stage) + coalesced binned2 write + gather1 ----
__global__ __launch_bounds__(256) void sortgather_kernel(const int* __restrict__ binned,
                                                         const int* __restrict__ bin_base,
                                                         const int* __restrict__ node_base,
                                                         const float* __restrict__ xpad,
                                                         const float* __restrict__ W1,
                                                         const float* __restrict__ b1,
                                                         const float* __restrict__ W2,
                                                         float* __restrict__ zs,
                                                         int* __restrict__ binned2) {
    __shared__ int sedge[SCAP];
    __shared__ int st[NPB + 1];
    __shared__ int cur[NPB];
    int t = threadIdx.x, b = blockIdx.x;
    int s0 = bin_base[b], s1 = bin_base[b + 1];
    int tot = s1 - s0;
    int g = b * NPB + t;
    int mystart = (g < N_NODES) ? node_base[g] - s0 : tot;
    st[t] = mystart;
    cur[t] = mystart;
    if (t == 0) st[NPB] = tot;
    __syncthreads();
    // place into LDS (dst-sorted), 4-batched
    int e = s0 + t;
    for (; e + 3 * TB < s1; e += 4 * TB) {
        int v0 = binned[e], v1 = binned[e + TB], v2 = binned[e + 2 * TB], v3 = binned[e + 3 * TB];
        int r0 = atomicAdd(&cur[((unsigned)v0) >> 24], 1);
        int r1 = atomicAdd(&cur[((unsigned)v1) >> 24], 1);
        int r2 = atomicAdd(&cur[((unsigned)v2) >> 24], 1);
        int r3 = atomicAdd(&cur[((unsigned)v3) >> 24], 1);
        if (r0 < SCAP) sedge[r0] = v0 & 0x00FFFFFF;
        if (r1 < SCAP) sedge[r1] = v1 & 0x00FFFFFF;
        if (r2 < SCAP) sedge[r2] = v2 & 0x00FFFFFF;
        if (r3 < SCAP) sedge[r3] = v3 & 0x00FFFFFF;
    }
    for (; e < s1; e += TB) {
        int v = binned[e];
        int r = atomicAdd(&cur[((unsigned)v) >> 24], 1);
        if (r < SCAP) sedge[r] = v & 0x00FFFFFF;
    }
    __syncthreads();
    // coalesced writeout for gather2
    for (int i = t; i < tot; i += TB) binned2[s0 + i] = sedge[i];
    // gather phase: thread = node, run in LDS, xpad rows pre-scaled by dinv
    if (g < N_NODES) {
        int a = st[t], a1 = st[t + 1];
        const float* own = xpad + (size_t)g * 8;
        float4 o4 = *(const float4*)own;
        float acc0 = o4.x, acc1 = o4.y, acc2 = o4.z, acc3 = o4.w, acc4 = own[4];
        float dd = own[5];
        int i = a;
        for (; i + 3 < a1; i += 4) {
            int n0 = sedge[i], n1 = sedge[i + 1], n2 = sedge[i + 2], n3 = sedge[i + 3];
            const float* r0 = xpad + (size_t)n0 * 8;
            const float* r1 = xpad + (size_t)n1 * 8;
            const float* r2 = xpad + (size_t)n2 * 8;
            const float* r3 = xpad + (size_t)n3 * 8;
            float4 q0 = *(const float4*)r0, q1 = *(const float4*)r1;
            float4 q2 = *(const float4*)r2, q3 = *(const float4*)r3;
            float c0 = r0[4], c1 = r1[4], c2 = r2[4], c3 = r3[4];
            acc0 += (q0.x + q1.x) + (q2.x + q3.x);
            acc1 += (q0.y + q1.y) + (q2.y + q3.y);
            acc2 += (q0.z + q1.z) + (q2.z + q3.z);
            acc3 += (q0.w + q1.w) + (q2.w + q3.w);
            acc4 += (c0 + c1) + (c2 + c3);
        }
        for (; i < a1; ++i) {
            const float* r = xpad + (size_t)sedge[i] * 8;
            float4 q = *(const float4*)r;
            acc0 += q.x; acc1 += q.y; acc2 += q.z; acc3 += q.w; acc4 += r[4];
        }
        float a0 = dd * acc0, a1f = dd * acc1, a2 = dd * acc2, a3 = dd * acc3, a4 = dd * acc4;
        float p = 0.f;
#pragma unroll
        for (int f = 0; f < F1; ++f) {
            float h = b1[f] + a0 * W1[0 * F1 + f] + a1f * W1[1 * F1 + f] + a2 * W1[2 * F1 + f]
                            + a3 * W1[3 * F1 + f] + a4 * W1[4 * F1 + f];
            p += fmaxf(h, 0.f) * W2[f];
        }
        zs[g] = dd * p;   // zs = dinv * z
    }
}

// ---- 7: layer-2 gather: thread-per-node, out = dd*(sum zs[s] + zs[d]) + b2 ----
__global__ __launch_bounds__(256) void gather2_kernel(const int* __restrict__ binned2,
                                                      const int* __restrict__ node_base,
                                                      const float* __restrict__ zs,
                                                      const float* __restrict__ xpad,
                                                      const float* __restrict__ b2,
                                                      float* __restrict__ out) {
    int g = blockIdx.x * TB + threadIdx.x;
    if (g >= N_NODES) return;
    int s = node_base[g], e1 = node_base[g + 1];
    float acc = zs[g];   // self term
    int e = s;
    for (; e + 3 < e1; e += 4) {
        float z0 = zs[binned2[e]], z1 = zs[binned2[e + 1]];
        float z2 = zs[binned2[e + 2]], z3 = zs[binned2[e + 3]];
        acc += (z0 + z1) + (z2 + z3);
    }
    for (; e < e1; ++e) acc += zs[binned2[e]];
    out[g] = xpad[(size_t)g * 8 + 5] * acc + b2[0];
}

extern "C" void kernel_launch(void* const* d_in, const int* in_sizes, int n_in,
                              void* d_out, int out_size, void* d_ws, size_t ws_size,
                              hipStream_t stream) {
    const float* x  = (const float*)d_in[0];
    const int*   ei = (const int*)d_in[1];   // int32 per harness contract
    const float* W1 = (const float*)d_in[2];
    const float* b1 = (const float*)d_in[3];
    const float* W2 = (const float*)d_in[4];
    const float* b2 = (const float*)d_in[5];
    float* out = (float*)d_out;

    // ws (~30 MB): xpad[N*8] | binned[E] | binned2[E] | zs[N] | node_base[N+1]
    //            | tile_cnt[NT*NB] | bin_base[NB+1]
    float* xpad      = (float*)d_ws;
    int*   binned    = (int*)(xpad + (size_t)N_NODES * 8);
    int*   binned2   = binned + N_EDGES;
    float* zs        = (float*)(binned2 + N_EDGES);
    int*   node_base = (int*)(zs + N_NODES);
    int*   tile_cnt  = node_base + N_NODES + 1;
    int*   bin_base  = tile_cnt + NT * NB;

    const int4* src4 = (const int4*)ei;               // edge_index[0]
    const int4* dst4 = (const int4*)(ei + N_EDGES);   // edge_index[1]

    int gN = (N_NODES + TB - 1) / TB;     // 391

    binhist_kernel<<<NT, BTB, 0, stream>>>(dst4, tile_cnt);
    scanfuse_kernel<<<1, 512, 0, stream>>>(tile_cnt, bin_base);
    repack_kernel<<<gN, TB, 0, stream>>>(x, xpad);
    reorder_kernel<<<NT, BTB, 0, stream>>>(src4, dst4, tile_cnt, binned);
    degscale_kernel<<<NB, TB, 0, stream>>>(binned, bin_base, xpad, node_base);
    sortgather_kernel<<<NB, TB, 0, stream>>>(binned, bin_base, node_base, xpad,
                                             W1, b1, W2, zs, binned2);
    gather2_kernel<<<gN, TB, 0, stream>>>(binned2, node_base, zs, xpad, b2, out);
}